// Round 13
// baseline (441.884 us; speedup 1.0000x reference)
//
#include <hip/hip_runtime.h>
#include <hip/hip_bf16.h>

// Decoder (EGNN) on MI355X. pos==0 identity => stage-2/pos/counts dead.
// ROUND 12: k_edge wave-concurrency fix. r11/r12 counters: VALUBusy 33% at
// avg occupancy 19.5% (~1.5 alive waves/SIMD) -- per-wave stall ~75%
// (trans/MFMA dep chains + early waves parked at the barrier), nothing to
// fill the slots. Latency-depth attacks (r11/r12) were null; the unpushed
// axis is WAVES. k_edge: 512-thread blocks (8 waves/node, stride-8 edges)
// -> 8192 waves, up to 7/SIMD resident (VGPR 72), per-wave tail halved.
// 1-deep prefetch (r10 form). k_post (LDS-staged W) confirmed <~10us, kept.

namespace {

constexpr int kE = 32768, kLat = 128;

typedef __attribute__((ext_vector_type(8))) short short8;   // 8 bf16
typedef __attribute__((ext_vector_type(4))) float floatx4;

__device__ __forceinline__ unsigned short f2bf(float f){   // RNE
  union { float f; unsigned int u; } v; v.f = f;
  unsigned int r = v.u + 0x7fffu + ((v.u >> 16) & 1u);
  return (unsigned short)(r >> 16);
}
__device__ __forceinline__ unsigned int packbf(float a, float b){
  return ((unsigned int)f2bf(b) << 16) | (unsigned int)f2bf(a);
}
__device__ __forceinline__ unsigned int pack2f(float a, float b){ // fast half-up
  unsigned int ua = __float_as_uint(a) + 0x8000u;
  unsigned int ub = __float_as_uint(b) + 0x8000u;
  return __builtin_amdgcn_perm(ub, ua, 0x07060302);
}
__device__ __forceinline__ float bflo(unsigned int u){
  union { unsigned int u; float f; } v; v.u = u << 16; return v.f;
}
__device__ __forceinline__ float bfhi(unsigned int u){
  union { unsigned int u; float f; } v; v.u = u & 0xffff0000u; return v.f;
}
__device__ __forceinline__ float silu2(float x){   // 2 trans + 3 alu
  float u = __builtin_amdgcn_exp2f(-1.44269504f * x);
  return x * __builtin_amdgcn_rcpf(1.0f + u);
}

// stage 16KB weight matrix into LDS with all 256 threads
__device__ __forceinline__ void stage16k(float* Wl, const float* src, int tid){
  const float4* p = (const float4*)src;
  float4* d = (float4*)Wl;
  d[tid]       = p[tid];
  d[tid + 256] = p[tid + 256];
  d[tid + 512] = p[tid + 512];
  d[tid + 768] = p[tid + 768];
}
// 64-row GEMM, W in LDS, X transposed in LDS [64 feat][64 rows + pad4] s68
__device__ __forceinline__ void gemm64(const float* Wl, const float* Xl,
                                       int j0, int r0, float acc[4][4]){
  #pragma unroll 4
  for (int k = 0; k < 64; k++){
    float4 w = *(const float4*)(Wl + k*64 + j0);
    float4 x = *(const float4*)(Xl + k*68 + r0);
    float xv[4] = { x.x, x.y, x.z, x.w };
    float wv[4] = { w.x, w.y, w.z, w.w };
    #pragma unroll
    for (int i = 0; i < 4; i++)
      #pragma unroll
      for (int j = 0; j < 4; j++)
        acc[i][j] += xv[i]*wv[j];
  }
}

// ---- CSR count+scan (1 block) + g = z@Wg+bg ------------------------------
__global__ void k_scancnt(const int* ei, int* off, int* fill,
                          const float* z, const float* Wg, const float* bg,
                          float* g){
  __shared__ int s0[1024];
  __shared__ int s1[1024];
  int t = threadIdx.x;
  s0[t] = 0; fill[t] = 0;
  __syncthreads();
  #pragma unroll
  for (int i = 0; i < 32; i++) atomicAdd(&s0[ei[i*1024 + t]], 1);
  __syncthreads();
  int c = s0[t];
  int* src = s0; int* dst = s1;
  for (int o = 1; o < 1024; o <<= 1){
    int v = src[t] + ((t >= o) ? src[t-o] : 0);
    dst[t] = v; __syncthreads();
    int* tmp = src; src = dst; dst = tmp;
  }
  int inc = src[t];
  off[t] = inc - c;
  if (t == 1023) off[1024] = inc;
  int b = t >> 6, j = t & 63;
  float acc = bg[j];
  for (int k = 0; k < kLat; k++) acc += z[b*kLat + k] * Wg[k*64 + j];
  g[b*64 + j] = acc;
}

// ---- bucket + wfrag (0-3) + An (4-67) + Ag (68) ---------------------------
__global__ void k_bucket(const int* ei, const int* off, int* fill, int* ecol,
                         const float* eW2, unsigned short* wfragE,
                         const float* nf, const float* Wn, const float* bn,
                         const float* eW1, const float* eb1, const float* g,
                         float* An1, float* An2, float* Ag1, float* Ag2){
  __shared__ __align__(16) float W0[4096];
  __shared__ __align__(16) float W1[4096];
  __shared__ __align__(16) float HR[16*68];
  int tid = threadIdx.x, bid = blockIdx.x;
  int e = bid*256 + tid;
  int r = ei[e];
  int s = atomicAdd(&fill[r], 1);
  ecol[off[r] + s] = ei[kE + e];
  if (bid < 4){
    int l = bid;
    for (int i = tid; i < 4096; i += 256){
      int f = i >> 9, lane = (i >> 3) & 63, j8 = i & 7;
      int jt = f >> 1, ks = f & 1;
      int k = ks*32 + (lane >> 4)*8 + j8;
      int j = jt*16 + (lane & 15);
      wfragE[l*4096 + i] = f2bf(eW2[l*4096 + k*64 + j]);
    }
  } else if (bid < 68){               // An = (nf@Wn+bn) @ eW1[0]
    const float4* e1a = (const float4*)(eW1);
    const float4* e1b = (const float4*)(eW1 + 4096);
    for (int i = tid; i < 1024; i += 256){
      ((float4*)W0)[i] = e1a[i]; ((float4*)W1)[i] = e1b[i];
    }
    int rl = tid >> 4, c = tid & 15, j0 = c*4;
    int n = (bid - 4)*16 + rl;
    float f0 = nf[n*3], f1 = nf[n*3+1], f2 = nf[n*3+2];
    float4 hv;
    hv.x = f0*Wn[j0+0] + f1*Wn[64+j0+0] + f2*Wn[128+j0+0] + bn[j0+0];
    hv.y = f0*Wn[j0+1] + f1*Wn[64+j0+1] + f2*Wn[128+j0+1] + bn[j0+1];
    hv.z = f0*Wn[j0+2] + f1*Wn[64+j0+2] + f2*Wn[128+j0+2] + bn[j0+2];
    hv.w = f0*Wn[j0+3] + f1*Wn[64+j0+3] + f2*Wn[128+j0+3] + bn[j0+3];
    *(float4*)(HR + rl*68 + j0) = hv;
    __syncthreads();
    float4 b1 = *(const float4*)(eb1 + j0);
    float a1[4] = { b1.x, b1.y, b1.z, b1.w };
    float a2[4] = { 0.f, 0.f, 0.f, 0.f };
    #pragma unroll 8
    for (int k = 0; k < 64; k++){
      float hk = HR[rl*68 + k];
      float4 w1 = *(const float4*)(W0 + k*64 + j0);
      float4 w2 = *(const float4*)(W1 + k*64 + j0);
      a1[0] += hk*w1.x; a1[1] += hk*w1.y; a1[2] += hk*w1.z; a1[3] += hk*w1.w;
      a2[0] += hk*w2.x; a2[1] += hk*w2.y; a2[2] += hk*w2.z; a2[3] += hk*w2.w;
    }
    float4 o1 = { a1[0], a1[1], a1[2], a1[3] };
    float4 o2 = { a2[0], a2[1], a2[2], a2[3] };
    *(float4*)(An1 + n*64 + j0) = o1;
    *(float4*)(An2 + n*64 + j0) = o2;
  } else if (bid == 68){              // Ag = g @ eW1[0]
    int bb = tid >> 4, j0 = (tid & 15)*4;
    float a1[4] = {0.f,0.f,0.f,0.f}, a2[4] = {0.f,0.f,0.f,0.f};
    for (int k = 0; k < 64; k++){
      float gk = g[bb*64 + k];
      float4 w1 = *(const float4*)(eW1 + k*64 + j0);
      float4 w2 = *(const float4*)(eW1 + 4096 + k*64 + j0);
      a1[0] += gk*w1.x; a1[1] += gk*w1.y; a1[2] += gk*w1.z; a1[3] += gk*w1.w;
      a2[0] += gk*w2.x; a2[1] += gk*w2.y; a2[2] += gk*w2.z; a2[3] += gk*w2.w;
    }
    float4 o1 = { a1[0], a1[1], a1[2], a1[3] };
    float4 o2 = { a2[0], a2[1], a2[2], a2[3] };
    *(float4*)(Ag1 + bb*64 + j0) = o1;
    *(float4*)(Ag2 + bb*64 + j0) = o2;
  }
}

// ---- k_pre1: materialize h = nf@Wn+bn+g, A1 = An1+Ag1, A2 = bf16(An2+Ag2) --
__global__ __launch_bounds__(256, 1) void k_pre1(const float* nf, const float* Wn,
      const float* bn, const float* g, const float* An1, const float* An2,
      const float* Ag1, const float* Ag2, float* h, float* A1,
      unsigned short* A2){
  int idx = blockIdx.x*256 + threadIdx.x;
  int row = idx >> 4;          // n*16 + bb
  int j0  = (idx & 15) * 4;
  int n = row >> 4, bb = row & 15;
  float4 a1 = *(const float4*)(An1 + n*64 + j0);
  float4 g1 = *(const float4*)(Ag1 + bb*64 + j0);
  a1.x += g1.x; a1.y += g1.y; a1.z += g1.z; a1.w += g1.w;
  *(float4*)(A1 + row*64 + j0) = a1;
  float4 a2 = *(const float4*)(An2 + n*64 + j0);
  float4 g2 = *(const float4*)(Ag2 + bb*64 + j0);
  a2.x += g2.x; a2.y += g2.y; a2.z += g2.z; a2.w += g2.w;
  uint2 pk; pk.x = packbf(a2.x, a2.y); pk.y = packbf(a2.z, a2.w);
  *(uint2*)(A2 + row*64 + j0) = pk;
  float f0 = nf[n*3], f1 = nf[n*3+1], f2 = nf[n*3+2];
  float4 w0 = *(const float4*)(Wn + j0);
  float4 w1 = *(const float4*)(Wn + 64 + j0);
  float4 w2 = *(const float4*)(Wn + 128 + j0);
  float4 bv = *(const float4*)(bn + j0);
  float4 gv = *(const float4*)(g + bb*64 + j0);
  float4 hv;
  hv.x = f0*w0.x + f1*w1.x + f2*w2.x + bv.x + gv.x;
  hv.y = f0*w0.y + f1*w1.y + f2*w2.y + bv.y + gv.y;
  hv.z = f0*w0.z + f1*w1.z + f2*w2.z + bv.z + gv.z;
  hv.w = f0*w0.w + f1*w1.w + f2*w2.w + bv.w + gv.w;
  *(float4*)(h + (bb*1024 + n)*64 + j0) = hv;
}

// ---- k_edge: 1024 blocks x 512 thr (8 waves/node, stride-8 edges) ---------
__global__ __launch_bounds__(512) void k_edge(int l,
      const float* A1r, const unsigned short* A2r,
      const unsigned short* wfragE, const float* eb2,
      const int* off, const int* ecol, float* AG){
  __shared__ __align__(16) float AGL[64*20];
  int tid = threadIdx.x, nd = blockIdx.x;
  int lane = tid & 63, wv = tid >> 6, m = lane & 15, quad = lane >> 4;

  for (int i = tid; i < 64*20; i += 512) AGL[i] = 0.f;
  __syncthreads();
  {
    short8 wf[8];
    #pragma unroll
    for (int f = 0; f < 8; f++)
      wf[f] = *(const short8*)(wfragE + l*4096 + f*512 + lane*8);
    floatx4 dini[4], agg[4];
    #pragma unroll
    for (int jt = 0; jt < 4; jt++){
      dini[jt] = *(const floatx4*)(eb2 + l*64 + jt*16 + quad*4);
      agg[jt] = (floatx4){0.f,0.f,0.f,0.f};
    }
    int e0 = off[nd] + wv, e1 = off[nd+1];
    if (e0 < e1){
      float4 a1[4];
      #pragma unroll
      for (int ks = 0; ks < 2; ks++){
        a1[ks*2+0] = *(const float4*)(A1r + (nd<<10) + (m<<6) + ks*32 + quad*8);
        a1[ks*2+1] = *(const float4*)(A1r + (nd<<10) + (m<<6) + ks*32 + quad*8 + 4);
      }
      int c0 = ecol[e0];
      uint4 p0 = *(const uint4*)(A2r + ((c0<<4)+m)*64 + quad*8);
      uint4 p1 = *(const uint4*)(A2r + ((c0<<4)+m)*64 + 32 + quad*8);
      for (int e = e0; e < e1; e += 8){
        uint4 c_0 = p0, c_1 = p1;
        if (e + 8 < e1){
          int cn = ecol[e+8];
          p0 = *(const uint4*)(A2r + ((cn<<4)+m)*64 + quad*8);
          p1 = *(const uint4*)(A2r + ((cn<<4)+m)*64 + 32 + quad*8);
        }
        short8 bfr[2];
        #pragma unroll
        for (int ks = 0; ks < 2; ks++){
          uint4 a2r = (ks == 0) ? c_0 : c_1;
          float4 x0 = a1[ks*2+0];
          float4 x1 = a1[ks*2+1];
          float v0 = silu2(x0.x + bflo(a2r.x));
          float v1 = silu2(x0.y + bfhi(a2r.x));
          float v2 = silu2(x0.z + bflo(a2r.y));
          float v3 = silu2(x0.w + bfhi(a2r.y));
          float v4 = silu2(x1.x + bflo(a2r.z));
          float v5 = silu2(x1.y + bfhi(a2r.z));
          float v6 = silu2(x1.z + bflo(a2r.w));
          float v7 = silu2(x1.w + bfhi(a2r.w));
          union { uint4 u; short8 s; } bu;
          bu.u.x = pack2f(v0, v1); bu.u.y = pack2f(v2, v3);
          bu.u.z = pack2f(v4, v5); bu.u.w = pack2f(v6, v7);
          bfr[ks] = bu.s;
        }
        #pragma unroll
        for (int jt = 0; jt < 4; jt++){
          floatx4 d = dini[jt];
          d = __builtin_amdgcn_mfma_f32_16x16x32_bf16(wf[jt*2+0], bfr[0], d, 0, 0, 0);
          d = __builtin_amdgcn_mfma_f32_16x16x32_bf16(wf[jt*2+1], bfr[1], d, 0, 0, 0);
          floatx4 a = agg[jt];
          a.x += silu2(d.x); a.y += silu2(d.y);
          a.z += silu2(d.z); a.w += silu2(d.w);
          agg[jt] = a;
        }
      }
      #pragma unroll
      for (int jt = 0; jt < 4; jt++)
        #pragma unroll
        for (int i = 0; i < 4; i++)
          atomicAdd(&AGL[(jt*16 + quad*4 + i)*20 + m], agg[jt][i]);
    }
  }
  __syncthreads();
  // AGL [feat][16 batch] -> AG[nd*1024 + f*16 + b]
  if (tid < 256){
    int f = tid >> 2, b4 = (tid & 3) * 4;
    float4 v = *(const float4*)(AGL + f*20 + b4);
    *(float4*)(AG + nd*1024 + f*16 + b4) = v;
  }
}

// ---- k_post: 256 blocks x 256 thr; block = 4 nodes x 16 batches (64 rows) --
// LDS-staged W (once per matrix), all threads gemm 4x4 tiles.
template <bool LAST>
__global__ __launch_bounds__(256) void k_post(int l,
      const float* AG, float* h, float* A1w, unsigned short* A2w,
      const float* nW1, const float* nb1_, const float* nW2, const float* nb2_,
      const float* lng_, const float* lnb_, const float* eW1, const float* eb1_,
      const float* oW1, const float* ob1_, const float* oW2, const float* ob2_,
      float* out){
  __shared__ __align__(16) float W[4096];
  __shared__ __align__(16) float XT[64*68];
  __shared__ __align__(16) float AGT[64*68];
  __shared__ float W2o[192];
  __shared__ float ob2s[4];
  int tid = threadIdx.x, bid = blockIdx.x;
  int n0 = bid * 4;
  int c = tid & 15, gq = tid >> 4;
  int j0 = c*4, r0 = gq*4;

  stage16k(W, nW1 + l*8192, tid);             // W := nW1lo
  // XT := h^T  (rows rr = q*16+b)
  for (int i = tid; i < 1024; i += 256){
    int f4 = i >> 6, rr = i & 63;
    int q = rr >> 4, b = rr & 15;
    float4 v = *(const float4*)(h + (b*1024 + n0 + q)*64 + f4*4);
    XT[(f4*4+0)*68 + rr] = v.x;
    XT[(f4*4+1)*68 + rr] = v.y;
    XT[(f4*4+2)*68 + rr] = v.z;
    XT[(f4*4+3)*68 + rr] = v.w;
  }
  // AGT := AG^T (AG already [f][b] per node)
  for (int i = tid; i < 1024; i += 256){
    int q = i >> 8, j = i & 255, f = j >> 2, b4 = (j & 3)*4;
    float4 v = *(const float4*)(AG + (n0+q)*1024 + f*16 + b4);
    *(float4*)(AGT + f*68 + q*16 + b4) = v;
  }
  float acc[4][4];
  { float4 b1 = *(const float4*)(nb1_ + l*64 + j0);
    float bv[4] = { b1.x, b1.y, b1.z, b1.w };
    #pragma unroll
    for (int i = 0; i < 4; i++)
      #pragma unroll
      for (int j = 0; j < 4; j++) acc[i][j] = bv[j]; }
  __syncthreads();                            // B1
  gemm64(W, XT, j0, r0, acc);                 // t = h @ nW1lo + b1
  float hold[4][4];
  #pragma unroll
  for (int i = 0; i < 4; i++)
    #pragma unroll
    for (int j = 0; j < 4; j++) hold[i][j] = XT[(j0+j)*68 + r0+i];
  __syncthreads();                            // B2 (XT/W readers done)
  stage16k(W, nW1 + l*8192 + 4096, tid);      // W := nW1hi
  __syncthreads();                            // B3
  gemm64(W, AGT, j0, r0, acc);                // t += agg @ nW1hi
  #pragma unroll
  for (int i = 0; i < 4; i++)
    #pragma unroll
    for (int j = 0; j < 4; j++) acc[i][j] = silu2(acc[i][j]);
  #pragma unroll
  for (int j = 0; j < 4; j++){                // XT := t^T (safe: XT idle)
    float4 t = { acc[0][j], acc[1][j], acc[2][j], acc[3][j] };
    *(float4*)(XT + (j0 + j)*68 + r0) = t;
  }
  __syncthreads();                            // B4 (W readers + XT writes)
  stage16k(W, nW2 + l*4096, tid);             // W := nW2
  __syncthreads();                            // B5
  float u4[4][4];
  { float4 b2 = *(const float4*)(nb2_ + l*64 + j0);
    float bv[4] = { b2.x, b2.y, b2.z, b2.w };
    #pragma unroll
    for (int i = 0; i < 4; i++)
      #pragma unroll
      for (int j = 0; j < 4; j++) u4[i][j] = bv[j]; }
  gemm64(W, XT, j0, r0, u4);                  // u = t @ nW2 + nb2
  float4 lgv = *(const float4*)(lng_ + l*64 + j0);
  float4 lbv = *(const float4*)(lnb_ + l*64 + j0);
  float hn[4][4];
  #pragma unroll
  for (int i = 0; i < 4; i++){
    float hv[4];
    #pragma unroll
    for (int j = 0; j < 4; j++) hv[j] = hold[i][j] + u4[i][j];
    float s1 = hv[0]+hv[1]+hv[2]+hv[3];
    float s2 = hv[0]*hv[0]+hv[1]*hv[1]+hv[2]*hv[2]+hv[3]*hv[3];
    s1 += __shfl_xor(s1, 1, 64); s1 += __shfl_xor(s1, 2, 64);
    s1 += __shfl_xor(s1, 4, 64); s1 += __shfl_xor(s1, 8, 64);
    s2 += __shfl_xor(s2, 1, 64); s2 += __shfl_xor(s2, 2, 64);
    s2 += __shfl_xor(s2, 4, 64); s2 += __shfl_xor(s2, 8, 64);
    float mu  = s1 * (1.0f/64.0f);
    float var = s2 * (1.0f/64.0f) - mu*mu;
    float rs  = rsqrtf(var + 1e-5f);
    hn[i][0] = (hv[0]-mu)*rs*lgv.x + lbv.x;
    hn[i][1] = (hv[1]-mu)*rs*lgv.y + lbv.y;
    hn[i][2] = (hv[2]-mu)*rs*lgv.z + lbv.z;
    hn[i][3] = (hv[3]-mu)*rs*lgv.w + lbv.w;
  }
  __syncthreads();                            // B6 (G2 XT readers done)
  if (!LAST){
    stage16k(W, eW1 + (l+1)*8256, tid);       // W := eW1lo(l+1)
    #pragma unroll
    for (int i = 0; i < 4; i++){
      int rr = r0 + i;
      int q = rr >> 4, b = rr & 15;
      float4 v = { hn[i][0], hn[i][1], hn[i][2], hn[i][3] };
      *(float4*)(h + (b*1024 + n0 + q)*64 + j0) = v;
    }
    #pragma unroll
    for (int j = 0; j < 4; j++){              // XT := hn^T
      float4 t = { hn[0][j], hn[1][j], hn[2][j], hn[3][j] };
      *(float4*)(XT + (j0 + j)*68 + r0) = t;
    }
    float a1r[4][4];
    { float4 b1 = *(const float4*)(eb1_ + (l+1)*64 + j0);
      float bv[4] = { b1.x, b1.y, b1.z, b1.w };
      #pragma unroll
      for (int i = 0; i < 4; i++)
        #pragma unroll
        for (int j = 0; j < 4; j++) a1r[i][j] = bv[j]; }
    __syncthreads();                          // B7
    gemm64(W, XT, j0, r0, a1r);               // A1 = hn @ eW1lo + eb1
    __syncthreads();                          // B8
    stage16k(W, eW1 + (l+1)*8256 + 4096, tid);// W := eW1hi(l+1)
    float a2r[4][4];
    #pragma unroll
    for (int i = 0; i < 4; i++)
      #pragma unroll
      for (int j = 0; j < 4; j++) a2r[i][j] = 0.f;
    __syncthreads();                          // B9
    gemm64(W, XT, j0, r0, a2r);               // A2 = hn @ eW1hi
    #pragma unroll
    for (int i = 0; i < 4; i++){
      int rr = r0 + i;
      int q = rr >> 4, b = rr & 15;
      int tb = ((n0+q)*16 + b)*64 + j0;
      float4 o1 = { a1r[i][0], a1r[i][1], a1r[i][2], a1r[i][3] };
      *(float4*)(A1w + tb) = o1;
      uint2 pk; pk.x = packbf(a2r[i][0], a2r[i][1]);
      pk.y = packbf(a2r[i][2], a2r[i][3]);
      *(uint2*)(A2w + tb) = pk;
    }
  } else {
    stage16k(W, oW1, tid);                    // W := oW1
    if (tid < 192) W2o[tid] = oW2[tid];
    if (tid < 3)   ob2s[tid] = ob2_[tid];
    #pragma unroll
    for (int j = 0; j < 4; j++){              // XT := hn^T
      float4 t = { hn[0][j], hn[1][j], hn[2][j], hn[3][j] };
      *(float4*)(XT + (j0 + j)*68 + r0) = t;
    }
    float tr[4][4];
    { float4 b1 = *(const float4*)(ob1_ + j0);
      float bv[4] = { b1.x, b1.y, b1.z, b1.w };
      #pragma unroll
      for (int i = 0; i < 4; i++)
        #pragma unroll
        for (int j = 0; j < 4; j++) tr[i][j] = bv[j]; }
    __syncthreads();                          // B7
    gemm64(W, XT, j0, r0, tr);                // t = hn @ oW1 + ob1
    #pragma unroll
    for (int i = 0; i < 4; i++)
      #pragma unroll
      for (int j = 0; j < 4; j++) tr[i][j] = fmaxf(tr[i][j], 0.f);
    float po[4][3];
    #pragma unroll
    for (int i = 0; i < 4; i++){ po[i][0]=0.f; po[i][1]=0.f; po[i][2]=0.f; }
    #pragma unroll
    for (int j = 0; j < 4; j++){
      float w0 = W2o[(j0+j)*3 + 0];
      float w1 = W2o[(j0+j)*3 + 1];
      float w2 = W2o[(j0+j)*3 + 2];
      #pragma unroll
      for (int i = 0; i < 4; i++){
        po[i][0] += tr[i][j]*w0;
        po[i][1] += tr[i][j]*w1;
        po[i][2] += tr[i][j]*w2;
      }
    }
    #pragma unroll
    for (int i = 0; i < 4; i++)
      #pragma unroll
      for (int uu = 0; uu < 3; uu++){
        float v = po[i][uu];
        v += __shfl_xor(v, 1, 64); v += __shfl_xor(v, 2, 64);
        v += __shfl_xor(v, 4, 64); v += __shfl_xor(v, 8, 64);
        po[i][uu] = v;
      }
    if (c == 0){
      #pragma unroll
      for (int i = 0; i < 4; i++){
        int rr = r0 + i;
        int q = rr >> 4, b = rr & 15;
        out[b*3072 + (n0+q)*3 + 0] = po[i][0] + ob2s[0];
        out[b*3072 + (n0+q)*3 + 1] = po[i][1] + ob2s[1];
        out[b*3072 + (n0+q)*3 + 2] = po[i][2] + ob2s[2];
      }
    }
  }
}

} // namespace

extern "C" void kernel_launch(void* const* d_in, const int* in_sizes, int n_in,
                              void* d_out, int out_size, void* d_ws, size_t ws_size,
                              hipStream_t stream){
  const float* z   = (const float*)d_in[0];
  const int*   ei  = (const int*)d_in[1];
  const float* nf  = (const float*)d_in[2];
  const float* Wg  = (const float*)d_in[3];  const float* bg  = (const float*)d_in[4];
  const float* Wn  = (const float*)d_in[5];  const float* bn  = (const float*)d_in[6];
  const float* eW1 = (const float*)d_in[7];  const float* eb1 = (const float*)d_in[8];
  const float* eW2 = (const float*)d_in[9];  const float* eb2 = (const float*)d_in[10];
  const float* nW1 = (const float*)d_in[14]; const float* nb1 = (const float*)d_in[15];
  const float* nW2 = (const float*)d_in[16]; const float* nb2 = (const float*)d_in[17];
  const float* lng = (const float*)d_in[18]; const float* lnb = (const float*)d_in[19];
  const float* oW1 = (const float*)d_in[20]; const float* ob1 = (const float*)d_in[21];
  const float* oW2 = (const float*)d_in[22]; const float* ob2 = (const float*)d_in[23];

  float* W      = (float*)d_ws;
  float* h      = W;                                   // 1,048,576 f
  float* A1a    = W + 1048576;                         // 1,048,576 f
  float* A1b    = W + 2097152;                         // 1,048,576 f
  unsigned short* A2a    = (unsigned short*)(W + 3145728); // 1,048,576 bf16
  unsigned short* A2b    = (unsigned short*)(W + 3670016); // 1,048,576 bf16
  unsigned short* wfragE = (unsigned short*)(W + 4194304); // 16,384 bf16
  float* g      = W + 4202496;                         // 1,024 f
  float* An1    = W + 4203520;                         // 65,536 f
  float* An2    = W + 4269056;                         // 65,536 f
  float* Ag1    = W + 4334592;                         // 1,024 f
  float* Ag2    = W + 4335616;                         // 1,024 f
  int*   off    = (int*)(W + 4336640);                 // 1,025
  int*   fill   = off + 1025;                          // 1,024
  int*   ecol   = fill + 1024;                         // 32,768
  float* AG     = W + 4372480;                         // 1,048,576 f

  k_scancnt<<<1, 1024, 0, stream>>>(ei, off, fill, z, Wg, bg, g);
  k_bucket <<<128, 256, 0, stream>>>(ei, off, fill, ecol, eW2, wfragE,
                                     nf, Wn, bn, eW1, eb1, g, An1, An2, Ag1, Ag2);
  k_pre1   <<<1024,256, 0, stream>>>(nf, Wn, bn, g, An1, An2, Ag1, Ag2, h, A1a, A2a);

  for (int l = 0; l < 4; l++){
    const float* A1r = (l & 1) ? A1b : A1a;
    const unsigned short* A2r = (l & 1) ? A2b : A2a;
    float* A1w = (l & 1) ? A1a : A1b;
    unsigned short* A2w = (l & 1) ? A2a : A2b;
    k_edge<<<1024, 512, 0, stream>>>(l, A1r, A2r, wfragE, eb2, off, ecol, AG);
    if (l < 3)
      k_post<false><<<256, 256, 0, stream>>>(l, AG, h, A1w, A2w,
            nW1, nb1, nW2, nb2, lng, lnb, eW1, eb1,
            oW1, ob1, oW2, ob2, (float*)d_out);
    else
      k_post<true> <<<256, 256, 0, stream>>>(l, AG, h, A1w, A2w,
            nW1, nb1, nW2, nb2, lng, lnb, eW1, eb1,
            oW1, ob1, oW2, ob2, (float*)d_out);
  }
}

// Round 14
// 335.133 us; speedup vs baseline: 1.3185x; 1.3185x over previous
//
#include <hip/hip_runtime.h>
#include <hip/hip_bf16.h>

// Decoder (EGNN) on MI355X. pos==0 identity => stage-2/pos/counts dead.
// ROUND 14: revert to the session-best measured configuration (round-5
// fused kernel, 335.05us). Rationale: rounds 10-13 split edge/post for
// attribution -- edge phase = 46us/layer and resisted SIX structural
// attacks (prefetch depth x2: null; 8 waves: -36%; SIMD spread: null;
// granularity up/down: regressions). Integrated VALU-busy is ~15us-equiv
// regardless of config => a shared-resource latency wall (likely cross-XCD
// A2 resolution) not addressable from kernel structure. The split also
// pays ~40us extra launch gaps (11 vs 7 dispatches). Fused r5 form:
// 512 blocks x 2 nodes x 16 batches; edge = 4 waves (2/node, stride-2),
// AGL atomicAdd; post = threads 0-127 gemm 4x4 tiles, threads 128-255
// ping-pong stage next weight matrix (Wa/Wb); LDS ~51KB -> 2 blocks/CU.

namespace {

constexpr int kE = 32768, kLat = 128;

typedef __attribute__((ext_vector_type(8))) short short8;   // 8 bf16
typedef __attribute__((ext_vector_type(4))) float floatx4;

__device__ __forceinline__ unsigned short f2bf(float f){   // RNE
  union { float f; unsigned int u; } v; v.f = f;
  unsigned int r = v.u + 0x7fffu + ((v.u >> 16) & 1u);
  return (unsigned short)(r >> 16);
}
__device__ __forceinline__ unsigned int packbf(float a, float b){
  return ((unsigned int)f2bf(b) << 16) | (unsigned int)f2bf(a);
}
__device__ __forceinline__ unsigned int pack2f(float a, float b){ // fast half-up
  unsigned int ua = __float_as_uint(a) + 0x8000u;
  unsigned int ub = __float_as_uint(b) + 0x8000u;
  return __builtin_amdgcn_perm(ub, ua, 0x07060302);
}
__device__ __forceinline__ float bflo(unsigned int u){
  union { unsigned int u; float f; } v; v.u = u << 16; return v.f;
}
__device__ __forceinline__ float bfhi(unsigned int u){
  union { unsigned int u; float f; } v; v.u = u & 0xffff0000u; return v.f;
}
__device__ __forceinline__ float silu2(float x){   // 2 trans + 3 alu
  float u = __builtin_amdgcn_exp2f(-1.44269504f * x);
  return x * __builtin_amdgcn_rcpf(1.0f + u);
}

// stage 16KB weight block with the UPPER 128 threads (u = tid-128)
__device__ __forceinline__ void stageU(float* Wl, const float* src, int u){
  const float4* p = (const float4*)src;
  float4* d = (float4*)Wl;
  #pragma unroll
  for (int q = 0; q < 8; q++) d[u + q*128] = p[u + q*128];
}
// 32-row GEMM, X transposed [64 feat][32 rows + pad4] stride 36
__device__ __forceinline__ void gemm32(const float* Wl, const float* Xl,
                                       int j0, int r0, float acc[4][4]){
  #pragma unroll 4
  for (int k = 0; k < 64; k++){
    float4 w = *(const float4*)(Wl + k*64 + j0);
    float4 x = *(const float4*)(Xl + k*36 + r0);
    float xv[4] = { x.x, x.y, x.z, x.w };
    float wv[4] = { w.x, w.y, w.z, w.w };
    #pragma unroll
    for (int i = 0; i < 4; i++)
      #pragma unroll
      for (int j = 0; j < 4; j++)
        acc[i][j] += xv[i]*wv[j];
  }
}

// ---- CSR count+scan (1 block) + g = z@Wg+bg ------------------------------
__global__ void k_scancnt(const int* ei, int* off, int* fill,
                          const float* z, const float* Wg, const float* bg,
                          float* g){
  __shared__ int s0[1024];
  __shared__ int s1[1024];
  int t = threadIdx.x;
  s0[t] = 0; fill[t] = 0;
  __syncthreads();
  #pragma unroll
  for (int i = 0; i < 32; i++) atomicAdd(&s0[ei[i*1024 + t]], 1);
  __syncthreads();
  int c = s0[t];
  int* src = s0; int* dst = s1;
  for (int o = 1; o < 1024; o <<= 1){
    int v = src[t] + ((t >= o) ? src[t-o] : 0);
    dst[t] = v; __syncthreads();
    int* tmp = src; src = dst; dst = tmp;
  }
  int inc = src[t];
  off[t] = inc - c;
  if (t == 1023) off[1024] = inc;
  // g GEMM: thread t -> (batch t>>6, col t&63)
  int b = t >> 6, j = t & 63;
  float acc = bg[j];
  for (int k = 0; k < kLat; k++) acc += z[b*kLat + k] * Wg[k*64 + j];
  g[b*64 + j] = acc;
}

// ---- bucket + wfrag (0-3) + An (4-67) + Ag (68) ---------------------------
__global__ void k_bucket(const int* ei, const int* off, int* fill, int* ecol,
                         const float* eW2, unsigned short* wfragE,
                         const float* nf, const float* Wn, const float* bn,
                         const float* eW1, const float* eb1, const float* g,
                         float* An1, float* An2, float* Ag1, float* Ag2){
  __shared__ __align__(16) float W0[4096];
  __shared__ __align__(16) float W1[4096];
  __shared__ __align__(16) float HR[16*68];
  int tid = threadIdx.x, bid = blockIdx.x;
  int e = bid*256 + tid;
  int r = ei[e];
  int s = atomicAdd(&fill[r], 1);
  ecol[off[r] + s] = ei[kE + e];
  if (bid < 4){
    int l = bid;
    for (int i = tid; i < 4096; i += 256){
      int f = i >> 9, lane = (i >> 3) & 63, j8 = i & 7;
      int jt = f >> 1, ks = f & 1;
      int k = ks*32 + (lane >> 4)*8 + j8;
      int j = jt*16 + (lane & 15);
      wfragE[l*4096 + i] = f2bf(eW2[l*4096 + k*64 + j]);
    }
  } else if (bid < 68){               // An = (nf@Wn+bn) @ eW1[0]
    const float4* e1a = (const float4*)(eW1);
    const float4* e1b = (const float4*)(eW1 + 4096);
    for (int i = tid; i < 1024; i += 256){
      ((float4*)W0)[i] = e1a[i]; ((float4*)W1)[i] = e1b[i];
    }
    int rl = tid >> 4, c = tid & 15, j0 = c*4;
    int n = (bid - 4)*16 + rl;
    float f0 = nf[n*3], f1 = nf[n*3+1], f2 = nf[n*3+2];
    float4 hv;
    hv.x = f0*Wn[j0+0] + f1*Wn[64+j0+0] + f2*Wn[128+j0+0] + bn[j0+0];
    hv.y = f0*Wn[j0+1] + f1*Wn[64+j0+1] + f2*Wn[128+j0+1] + bn[j0+1];
    hv.z = f0*Wn[j0+2] + f1*Wn[64+j0+2] + f2*Wn[128+j0+2] + bn[j0+2];
    hv.w = f0*Wn[j0+3] + f1*Wn[64+j0+3] + f2*Wn[128+j0+3] + bn[j0+3];
    *(float4*)(HR + rl*68 + j0) = hv;
    __syncthreads();
    float4 b1 = *(const float4*)(eb1 + j0);
    float a1[4] = { b1.x, b1.y, b1.z, b1.w };
    float a2[4] = { 0.f, 0.f, 0.f, 0.f };
    #pragma unroll 8
    for (int k = 0; k < 64; k++){
      float hk = HR[rl*68 + k];
      float4 w1 = *(const float4*)(W0 + k*64 + j0);
      float4 w2 = *(const float4*)(W1 + k*64 + j0);
      a1[0] += hk*w1.x; a1[1] += hk*w1.y; a1[2] += hk*w1.z; a1[3] += hk*w1.w;
      a2[0] += hk*w2.x; a2[1] += hk*w2.y; a2[2] += hk*w2.z; a2[3] += hk*w2.w;
    }
    float4 o1 = { a1[0], a1[1], a1[2], a1[3] };
    float4 o2 = { a2[0], a2[1], a2[2], a2[3] };
    *(float4*)(An1 + n*64 + j0) = o1;
    *(float4*)(An2 + n*64 + j0) = o2;
  } else if (bid == 68){              // Ag = g @ eW1[0]
    int bb = tid >> 4, j0 = (tid & 15)*4;
    float a1[4] = {0.f,0.f,0.f,0.f}, a2[4] = {0.f,0.f,0.f,0.f};
    for (int k = 0; k < 64; k++){
      float gk = g[bb*64 + k];
      float4 w1 = *(const float4*)(eW1 + k*64 + j0);
      float4 w2 = *(const float4*)(eW1 + 4096 + k*64 + j0);
      a1[0] += gk*w1.x; a1[1] += gk*w1.y; a1[2] += gk*w1.z; a1[3] += gk*w1.w;
      a2[0] += gk*w2.x; a2[1] += gk*w2.y; a2[2] += gk*w2.z; a2[3] += gk*w2.w;
    }
    float4 o1 = { a1[0], a1[1], a1[2], a1[3] };
    float4 o2 = { a2[0], a2[1], a2[2], a2[3] };
    *(float4*)(Ag1 + bb*64 + j0) = o1;
    *(float4*)(Ag2 + bb*64 + j0) = o2;
  }
}

// ---- k_pre1: materialize h = nf@Wn+bn+g, A1 = An1+Ag1, A2 = bf16(An2+Ag2) --
__global__ __launch_bounds__(256, 1) void k_pre1(const float* nf, const float* Wn,
      const float* bn, const float* g, const float* An1, const float* An2,
      const float* Ag1, const float* Ag2, float* h, float* A1,
      unsigned short* A2){
  int idx = blockIdx.x*256 + threadIdx.x;
  int row = idx >> 4;          // n*16 + bb
  int j0  = (idx & 15) * 4;
  int n = row >> 4, bb = row & 15;
  float4 a1 = *(const float4*)(An1 + n*64 + j0);
  float4 g1 = *(const float4*)(Ag1 + bb*64 + j0);
  a1.x += g1.x; a1.y += g1.y; a1.z += g1.z; a1.w += g1.w;
  *(float4*)(A1 + row*64 + j0) = a1;
  float4 a2 = *(const float4*)(An2 + n*64 + j0);
  float4 g2 = *(const float4*)(Ag2 + bb*64 + j0);
  a2.x += g2.x; a2.y += g2.y; a2.z += g2.z; a2.w += g2.w;
  uint2 pk; pk.x = packbf(a2.x, a2.y); pk.y = packbf(a2.z, a2.w);
  *(uint2*)(A2 + row*64 + j0) = pk;
  float f0 = nf[n*3], f1 = nf[n*3+1], f2 = nf[n*3+2];
  float4 w0 = *(const float4*)(Wn + j0);
  float4 w1 = *(const float4*)(Wn + 64 + j0);
  float4 w2 = *(const float4*)(Wn + 128 + j0);
  float4 bv = *(const float4*)(bn + j0);
  float4 gv = *(const float4*)(g + bb*64 + j0);
  float4 hv;
  hv.x = f0*w0.x + f1*w1.x + f2*w2.x + bv.x + gv.x;
  hv.y = f0*w0.y + f1*w1.y + f2*w2.y + bv.y + gv.y;
  hv.z = f0*w0.z + f1*w1.z + f2*w2.z + bv.z + gv.z;
  hv.w = f0*w0.w + f1*w1.w + f2*w2.w + bv.w + gv.w;
  *(float4*)(h + (bb*1024 + n)*64 + j0) = hv;
}

// ---- k_layer: fused edge + node MLP + LN (+ next-A | head) -----------------
// 512 blocks x 256 thr. Block = 2 nodes x 16 batches (32 rows).
// Edge: 4 waves, wave wv -> node n0+(wv>>1), edges stride 2; AGL atomicAdd.
// Post: threads 0-127 gemm (4x4 tiles), threads 128-255 stage next W.
template <bool LAST>
__global__ __launch_bounds__(256) void k_layer(int l,
      const float* A1r, const unsigned short* A2r,
      float* A1w, unsigned short* A2w,
      float* h, const unsigned short* wfragE, const float* eb2,
      const int* off, const int* ecol,
      const float* nW1, const float* nb1_, const float* nW2, const float* nb2_,
      const float* lng_, const float* lnb_, const float* eW1, const float* eb1_,
      const float* oW1, const float* ob1_, const float* oW2, const float* ob2_,
      float* out){
  __shared__ __align__(16) float Wa[4096];
  __shared__ __align__(16) float Wb[4096];
  __shared__ __align__(16) float XT[64*36];
  __shared__ __align__(16) float AGL[64*36];
  __shared__ float W2o[192];
  __shared__ float ob2s[4];
  int tid = threadIdx.x, bid = blockIdx.x;
  int n0 = bid * 2;
  int lane = tid & 63, wv = tid >> 6, m = lane & 15, quad = lane >> 4;

  for (int i = tid; i < 64*36; i += 256) AGL[i] = 0.f;
  __syncthreads();

  // ---------------- edge phase ----------------
  {
    int nd = n0 + (wv >> 1);
    short8 wf[8];
    #pragma unroll
    for (int f = 0; f < 8; f++)
      wf[f] = *(const short8*)(wfragE + l*4096 + f*512 + lane*8);
    floatx4 dini[4], agg[4];
    #pragma unroll
    for (int jt = 0; jt < 4; jt++){
      dini[jt] = *(const floatx4*)(eb2 + l*64 + jt*16 + quad*4);
      agg[jt] = (floatx4){0.f,0.f,0.f,0.f};
    }
    int e0 = off[nd] + (wv & 1), e1 = off[nd+1];
    if (e0 < e1){
      float4 a1[4];
      #pragma unroll
      for (int ks = 0; ks < 2; ks++){
        a1[ks*2+0] = *(const float4*)(A1r + (nd<<10) + (m<<6) + ks*32 + quad*8);
        a1[ks*2+1] = *(const float4*)(A1r + (nd<<10) + (m<<6) + ks*32 + quad*8 + 4);
      }
      int c0 = ecol[e0];
      uint4 p0 = *(const uint4*)(A2r + ((c0<<4)+m)*64 + quad*8);
      uint4 p1 = *(const uint4*)(A2r + ((c0<<4)+m)*64 + 32 + quad*8);
      for (int e = e0; e < e1; e += 2){
        uint4 c_0 = p0, c_1 = p1;
        if (e + 2 < e1){
          int cn = ecol[e+2];
          p0 = *(const uint4*)(A2r + ((cn<<4)+m)*64 + quad*8);
          p1 = *(const uint4*)(A2r + ((cn<<4)+m)*64 + 32 + quad*8);
        }
        short8 bfr[2];
        #pragma unroll
        for (int ks = 0; ks < 2; ks++){
          uint4 a2r = (ks == 0) ? c_0 : c_1;
          float4 x0 = a1[ks*2+0];
          float4 x1 = a1[ks*2+1];
          float v0 = silu2(x0.x + bflo(a2r.x));
          float v1 = silu2(x0.y + bfhi(a2r.x));
          float v2 = silu2(x0.z + bflo(a2r.y));
          float v3 = silu2(x0.w + bfhi(a2r.y));
          float v4 = silu2(x1.x + bflo(a2r.z));
          float v5 = silu2(x1.y + bfhi(a2r.z));
          float v6 = silu2(x1.z + bflo(a2r.w));
          float v7 = silu2(x1.w + bfhi(a2r.w));
          union { uint4 u; short8 s; } bu;
          bu.u.x = pack2f(v0, v1); bu.u.y = pack2f(v2, v3);
          bu.u.z = pack2f(v4, v5); bu.u.w = pack2f(v6, v7);
          bfr[ks] = bu.s;
        }
        #pragma unroll
        for (int jt = 0; jt < 4; jt++){
          floatx4 d = dini[jt];
          d = __builtin_amdgcn_mfma_f32_16x16x32_bf16(wf[jt*2+0], bfr[0], d, 0, 0, 0);
          d = __builtin_amdgcn_mfma_f32_16x16x32_bf16(wf[jt*2+1], bfr[1], d, 0, 0, 0);
          floatx4 a = agg[jt];
          a.x += silu2(d.x); a.y += silu2(d.y);
          a.z += silu2(d.z); a.w += silu2(d.w);
          agg[jt] = a;
        }
      }
    }
    int rloc = (wv >> 1)*16 + m;
    #pragma unroll
    for (int jt = 0; jt < 4; jt++)
      #pragma unroll
      for (int i = 0; i < 4; i++)
        atomicAdd(&AGL[(jt*16 + quad*4 + i)*36 + rloc], agg[jt][i]);
  }

  // ---------------- post: lower 128 gemm, upper 128 stage ----------------
  bool lo = (tid < 128);
  int up = tid - 128;
  int c = tid & 15, gq = tid >> 4;      // gq in 0..7 for lo threads
  int j0 = c*4, r0 = gq*4;

  float hold[4][4];
  float acc[4][4];
  if (lo){
    #pragma unroll
    for (int i = 0; i < 4; i++){
      int rr = r0 + i;
      int nd2 = n0 + (rr >> 4), bb = rr & 15;
      float4 v = *(const float4*)(h + (bb*1024 + nd2)*64 + j0);
      hold[i][0]=v.x; hold[i][1]=v.y; hold[i][2]=v.z; hold[i][3]=v.w;
    }
    #pragma unroll
    for (int j = 0; j < 4; j++){
      float4 t = { hold[0][j], hold[1][j], hold[2][j], hold[3][j] };
      *(float4*)(XT + (j0 + j)*36 + r0) = t;
    }
    float4 b1 = *(const float4*)(nb1_ + l*64 + j0);
    float bv[4] = { b1.x, b1.y, b1.z, b1.w };
    #pragma unroll
    for (int i = 0; i < 4; i++)
      #pragma unroll
      for (int j = 0; j < 4; j++) acc[i][j] = bv[j];
  } else {
    stageU(Wa, nW1 + l*8192, up);
  }
  __syncthreads();                       // AGL + XT + Wa ready
  if (lo) gemm32(Wa, XT, j0, r0, acc);   // t += h @ nW1lo
  else    stageU(Wb, nW1 + l*8192 + 4096, up);
  __syncthreads();
  if (lo){
    gemm32(Wb, AGL, j0, r0, acc);        // t += agg @ nW1hi
    #pragma unroll
    for (int i = 0; i < 4; i++)
      #pragma unroll
      for (int j = 0; j < 4; j++) acc[i][j] = silu2(acc[i][j]);
    #pragma unroll
    for (int j = 0; j < 4; j++){
      float4 t = { acc[0][j], acc[1][j], acc[2][j], acc[3][j] };
      *(float4*)(XT + (j0 + j)*36 + r0) = t;
    }
  } else {
    stageU(Wa, nW2 + l*4096, up);
  }
  __syncthreads();
  float hn[4][4];
  if (lo){
    float u4[4][4];
    float4 b2 = *(const float4*)(nb2_ + l*64 + j0);
    float bv[4] = { b2.x, b2.y, b2.z, b2.w };
    #pragma unroll
    for (int i = 0; i < 4; i++)
      #pragma unroll
      for (int j = 0; j < 4; j++) u4[i][j] = bv[j];
    gemm32(Wa, XT, j0, r0, u4);          // u = t @ nW2 + nb2
    float4 lgv = *(const float4*)(lng_ + l*64 + j0);
    float4 lbv = *(const float4*)(lnb_ + l*64 + j0);
    #pragma unroll
    for (int i = 0; i < 4; i++){
      float hv[4];
      #pragma unroll
      for (int j = 0; j < 4; j++) hv[j] = hold[i][j] + u4[i][j];
      float s1 = hv[0]+hv[1]+hv[2]+hv[3];
      float s2 = hv[0]*hv[0]+hv[1]*hv[1]+hv[2]*hv[2]+hv[3]*hv[3];
      s1 += __shfl_xor(s1, 1, 64); s1 += __shfl_xor(s1, 2, 64);
      s1 += __shfl_xor(s1, 4, 64); s1 += __shfl_xor(s1, 8, 64);
      s2 += __shfl_xor(s2, 1, 64); s2 += __shfl_xor(s2, 2, 64);
      s2 += __shfl_xor(s2, 4, 64); s2 += __shfl_xor(s2, 8, 64);
      float mu  = s1 * (1.0f/64.0f);
      float var = s2 * (1.0f/64.0f) - mu*mu;
      float rs  = rsqrtf(var + 1e-5f);
      hn[i][0] = (hv[0]-mu)*rs*lgv.x + lbv.x;
      hn[i][1] = (hv[1]-mu)*rs*lgv.y + lbv.y;
      hn[i][2] = (hv[2]-mu)*rs*lgv.z + lbv.z;
      hn[i][3] = (hv[3]-mu)*rs*lgv.w + lbv.w;
    }
    if (!LAST){
      #pragma unroll
      for (int i = 0; i < 4; i++){
        int rr = r0 + i;
        int nd2 = n0 + (rr >> 4), bb = rr & 15;
        float4 v = { hn[i][0], hn[i][1], hn[i][2], hn[i][3] };
        *(float4*)(h + (bb*1024 + nd2)*64 + j0) = v;
      }
    }
    // hn -> AGL (AGL free after gemm2)
    #pragma unroll
    for (int j = 0; j < 4; j++){
      float4 t = { hn[0][j], hn[1][j], hn[2][j], hn[3][j] };
      *(float4*)(AGL + (j0 + j)*36 + r0) = t;
    }
  } else {
    if (!LAST){
      stageU(Wb, eW1 + (l+1)*8256, up);
    } else {
      stageU(Wb, oW1, up);
      W2o[up] = oW2[up];
      if (up < 64) W2o[128 + up] = oW2[128 + up];
      if (up < 3)  ob2s[up] = ob2_[up];
    }
  }
  __syncthreads();
  if (!LAST){
    float a1r[4][4];
    if (lo){
      float4 b1 = *(const float4*)(eb1_ + (l+1)*64 + j0);
      float bv[4] = { b1.x, b1.y, b1.z, b1.w };
      #pragma unroll
      for (int i = 0; i < 4; i++)
        #pragma unroll
        for (int j = 0; j < 4; j++) a1r[i][j] = bv[j];
      gemm32(Wb, AGL, j0, r0, a1r);      // A1 = hn @ eW1lo + eb1
    } else {
      stageU(Wa, eW1 + (l+1)*8256 + 4096, up);
    }
    __syncthreads();
    if (lo){
      float a2r[4][4];
      #pragma unroll
      for (int i = 0; i < 4; i++)
        #pragma unroll
        for (int j = 0; j < 4; j++) a2r[i][j] = 0.f;
      gemm32(Wa, AGL, j0, r0, a2r);      // A2 = hn @ eW1hi
      #pragma unroll
      for (int i = 0; i < 4; i++){
        int rr = r0 + i;
        int nd2 = n0 + (rr >> 4), bb = rr & 15;
        int tb = (nd2*16 + bb)*64 + j0;
        float4 o1 = { a1r[i][0], a1r[i][1], a1r[i][2], a1r[i][3] };
        *(float4*)(A1w + tb) = o1;
        uint2 pk; pk.x = packbf(a2r[i][0], a2r[i][1]);
        pk.y = packbf(a2r[i][2], a2r[i][3]);
        *(uint2*)(A2w + tb) = pk;
      }
    }
  } else {
    if (lo){
      float tr[4][4];
      float4 b1 = *(const float4*)(ob1_ + j0);
      float bv[4] = { b1.x, b1.y, b1.z, b1.w };
      #pragma unroll
      for (int i = 0; i < 4; i++)
        #pragma unroll
        for (int j = 0; j < 4; j++) tr[i][j] = bv[j];
      gemm32(Wb, AGL, j0, r0, tr);       // t = hn @ oW1 + ob1
      #pragma unroll
      for (int i = 0; i < 4; i++)
        #pragma unroll
        for (int j = 0; j < 4; j++) tr[i][j] = fmaxf(tr[i][j], 0.f);
      float po[4][3];
      #pragma unroll
      for (int i = 0; i < 4; i++){ po[i][0]=0.f; po[i][1]=0.f; po[i][2]=0.f; }
      #pragma unroll
      for (int j = 0; j < 4; j++){
        float w0 = W2o[(j0+j)*3 + 0];
        float w1 = W2o[(j0+j)*3 + 1];
        float w2 = W2o[(j0+j)*3 + 2];
        #pragma unroll
        for (int i = 0; i < 4; i++){
          po[i][0] += tr[i][j]*w0;
          po[i][1] += tr[i][j]*w1;
          po[i][2] += tr[i][j]*w2;
        }
      }
      #pragma unroll
      for (int i = 0; i < 4; i++)
        #pragma unroll
        for (int uu = 0; uu < 3; uu++){
          float v = po[i][uu];
          v += __shfl_xor(v, 1, 64); v += __shfl_xor(v, 2, 64);
          v += __shfl_xor(v, 4, 64); v += __shfl_xor(v, 8, 64);
          po[i][uu] = v;
        }
      if (c == 0){
        #pragma unroll
        for (int i = 0; i < 4; i++){
          int rr = r0 + i;
          int nd2 = n0 + (rr >> 4), bb = rr & 15;
          out[bb*3072 + nd2*3 + 0] = po[i][0] + ob2s[0];
          out[bb*3072 + nd2*3 + 1] = po[i][1] + ob2s[1];
          out[bb*3072 + nd2*3 + 2] = po[i][2] + ob2s[2];
        }
      }
    }
  }
}

} // namespace

extern "C" void kernel_launch(void* const* d_in, const int* in_sizes, int n_in,
                              void* d_out, int out_size, void* d_ws, size_t ws_size,
                              hipStream_t stream){
  const float* z   = (const float*)d_in[0];
  const int*   ei  = (const int*)d_in[1];
  const float* nf  = (const float*)d_in[2];
  const float* Wg  = (const float*)d_in[3];  const float* bg  = (const float*)d_in[4];
  const float* Wn  = (const float*)d_in[5];  const float* bn  = (const float*)d_in[6];
  const float* eW1 = (const float*)d_in[7];  const float* eb1 = (const float*)d_in[8];
  const float* eW2 = (const float*)d_in[9];  const float* eb2 = (const float*)d_in[10];
  const float* nW1 = (const float*)d_in[14]; const float* nb1 = (const float*)d_in[15];
  const float* nW2 = (const float*)d_in[16]; const float* nb2 = (const float*)d_in[17];
  const float* lng = (const float*)d_in[18]; const float* lnb = (const float*)d_in[19];
  const float* oW1 = (const float*)d_in[20]; const float* ob1 = (const float*)d_in[21];
  const float* oW2 = (const float*)d_in[22]; const float* ob2 = (const float*)d_in[23];

  float* W      = (float*)d_ws;
  float* h      = W;                                   // 1,048,576 f
  float* A1a    = W + 1048576;                         // 1,048,576 f
  float* A1b    = W + 2097152;                         // 1,048,576 f
  unsigned short* A2a    = (unsigned short*)(W + 3145728); // 1,048,576 bf16
  unsigned short* A2b    = (unsigned short*)(W + 3670016); // 1,048,576 bf16
  unsigned short* wfragE = (unsigned short*)(W + 4194304); // 16,384 bf16
  float* g      = W + 4202496;                         // 1,024 f
  float* An1    = W + 4203520;                         // 65,536 f
  float* An2    = W + 4269056;                         // 65,536 f
  float* Ag1    = W + 4334592;                         // 1,024 f
  float* Ag2    = W + 4335616;                         // 1,024 f
  int*   off    = (int*)(W + 4336640);                 // 1,025
  int*   fill   = off + 1025;                          // 1,024
  int*   ecol   = fill + 1024;                         // 32,768

  k_scancnt<<<1, 1024, 0, stream>>>(ei, off, fill, z, Wg, bg, g);
  k_bucket <<<128, 256, 0, stream>>>(ei, off, fill, ecol, eW2, wfragE,
                                     nf, Wn, bn, eW1, eb1, g, An1, An2, Ag1, Ag2);
  k_pre1   <<<1024,256, 0, stream>>>(nf, Wn, bn, g, An1, An2, Ag1, Ag2, h, A1a, A2a);

  for (int l = 0; l < 4; l++){
    const float* A1r = (l & 1) ? A1b : A1a;
    const unsigned short* A2r = (l & 1) ? A2b : A2a;
    float* A1w = (l & 1) ? A1a : A1b;
    unsigned short* A2w = (l & 1) ? A2a : A2b;
    if (l < 3)
      k_layer<false><<<512, 256, 0, stream>>>(l, A1r, A2r, A1w, A2w, h, wfragE,
            eb2, off, ecol, nW1, nb1, nW2, nb2, lng, lnb, eW1, eb1,
            oW1, ob1, oW2, ob2, (float*)d_out);
    else
      k_layer<true> <<<512, 256, 0, stream>>>(l, A1r, A2r, A1w, A2w, h, wfragE,
            eb2, off, ecol, nW1, nb1, nW2, nb2, lng, lnb, eW1, eb1,
            oW1, ob1, oW2, ob2, (float*)d_out);
  }
}